// Round 1
// baseline (2481.064 us; speedup 1.0000x reference)
//
#include <hip/hip_runtime.h>

#define BROWS 4096
#define DIMK 256
#define QN 32768
#define SCALE_T 10.0f                         // 1/TEMPERATURE
#define EXPSCALE 14.426950408889634f          // 10 * log2(e)

__device__ __forceinline__ unsigned int enc_f32(float f) {
    unsigned int b = __float_as_uint(f);
    return (b & 0x80000000u) ? ~b : (b | 0x80000000u);
}

__device__ __forceinline__ unsigned long long shfl_xor_u64(unsigned long long v, int off) {
    unsigned int lo = (unsigned int)(v & 0xFFFFFFFFull);
    unsigned int hi = (unsigned int)(v >> 32);
    lo = (unsigned int)__shfl_xor((int)lo, off, 64);
    hi = (unsigned int)__shfl_xor((int)hi, off, 64);
    return ((unsigned long long)hi << 32) | (unsigned long long)lo;
}

// h[i][j] = relu(sum_k f[i][k] * W[k][j] + bias[j]); one block per row
__global__ __launch_bounds__(256) void proj_relu(const float* __restrict__ F,
                                                 const float* __restrict__ W,
                                                 const float* __restrict__ bias,
                                                 float* __restrict__ H) {
    __shared__ float fr[DIMK];
    const int i = blockIdx.x, j = threadIdx.x;
    fr[j] = F[(size_t)i * DIMK + j];
    __syncthreads();
    float acc = bias[j];
#pragma unroll 8
    for (int k = 0; k < DIMK; ++k) acc = fmaf(fr[k], W[k * DIMK + j], acc);
    H[(size_t)i * DIMK + j] = acc > 0.f ? acc : 0.f;
}

// p[i][j] = (sum_k h[i][k]*W[k][j] + bias[j]) / max(||row||, 1e-12)
__global__ __launch_bounds__(256) void proj_norm(const float* __restrict__ H,
                                                 const float* __restrict__ W,
                                                 const float* __restrict__ bias,
                                                 float* __restrict__ P) {
    __shared__ float hr[DIMK];
    __shared__ float red[256];
    const int i = blockIdx.x, j = threadIdx.x;
    hr[j] = H[(size_t)i * DIMK + j];
    __syncthreads();
    float acc = bias[j];
#pragma unroll 8
    for (int k = 0; k < DIMK; ++k) acc = fmaf(hr[k], W[k * DIMK + j], acc);
    red[j] = acc * acc;
    __syncthreads();
    for (int s = 128; s > 0; s >>= 1) {
        if (j < s) red[j] += red[j + s];
        __syncthreads();
    }
    float denom = fmaxf(sqrtf(red[0]), 1e-12f);
    P[(size_t)i * DIMK + j] = acc / denom;
}

// 64x64 output tile, K=256 in 4 k-tiles of 64. Fused reduction:
// MODE 0: per-row argmax (packed u64 atomicMax), MODE 1: per-row sum(exp(dot*10))
template <int MODE>
__global__ __launch_bounds__(256) void tile_gemm_reduce(const float* __restrict__ A,
                                                        const float* __restrict__ Bm,
                                                        unsigned long long* __restrict__ packed,
                                                        float* __restrict__ sums) {
    __shared__ float As[64][68];  // k-major, +4 pad keeps 16B alignment, breaks bank collisions
    __shared__ float Bs[64][68];
    const int tid = threadIdx.x;
    const int tx = tid & 15, ty = tid >> 4;
    const int row0 = blockIdx.y * 64, col0 = blockIdx.x * 64;
    const int lr = tid >> 2;         // 0..63 row of tile for loads
    const int lc = (tid & 3) << 2;   // 0,4,8,12

    float acc[4][4] = {};

    for (int k0 = 0; k0 < DIMK; k0 += 64) {
#pragma unroll
        for (int l = 0; l < 4; ++l) {
            const int kk = lc + l * 16;
            float4 a = *(const float4*)&A[(size_t)(row0 + lr) * DIMK + k0 + kk];
            float4 b = *(const float4*)&Bm[(size_t)(col0 + lr) * DIMK + k0 + kk];
            As[kk + 0][lr] = a.x; As[kk + 1][lr] = a.y; As[kk + 2][lr] = a.z; As[kk + 3][lr] = a.w;
            Bs[kk + 0][lr] = b.x; Bs[kk + 1][lr] = b.y; Bs[kk + 2][lr] = b.z; Bs[kk + 3][lr] = b.w;
        }
        __syncthreads();
#pragma unroll
        for (int k = 0; k < 64; ++k) {
            float4 av = *(const float4*)&As[k][ty << 2];
            float4 bv = *(const float4*)&Bs[k][tx << 2];
            float a4[4] = {av.x, av.y, av.z, av.w};
            float b4[4] = {bv.x, bv.y, bv.z, bv.w};
#pragma unroll
            for (int i = 0; i < 4; ++i)
#pragma unroll
                for (int j = 0; j < 4; ++j) acc[i][j] = fmaf(a4[i], b4[j], acc[i][j]);
        }
        __syncthreads();
    }

    if (MODE == 0) {
#pragma unroll
        for (int i = 0; i < 4; ++i) {
            float bv = acc[i][0];
            int bj = 0;
#pragma unroll
            for (int j = 1; j < 4; ++j) {
                if (acc[i][j] > bv) { bv = acc[i][j]; bj = j; }
            }
            unsigned long long pk =
                ((unsigned long long)enc_f32(bv) << 32) |
                (unsigned long long)(0xFFFFFFFFu - (unsigned int)(col0 + (tx << 2) + bj));
#pragma unroll
            for (int off = 1; off < 16; off <<= 1) {
                unsigned long long o = shfl_xor_u64(pk, off);
                if (o > pk) pk = o;
            }
            if (tx == 0) atomicMax(&packed[row0 + (ty << 2) + i], pk);
        }
    } else {
#pragma unroll
        for (int i = 0; i < 4; ++i) {
            float s = 0.f;
#pragma unroll
            for (int j = 0; j < 4; ++j) s += exp2f(acc[i][j] * EXPSCALE);
#pragma unroll
            for (int off = 1; off < 16; off <<= 1) s += __shfl_xor(s, off, 64);
            if (tx == 0) atomicAdd(&sums[row0 + (ty << 2) + i], s);
        }
    }
}

__global__ __launch_bounds__(256) void gather_rows(const unsigned long long* __restrict__ packed,
                                                   const float* __restrict__ queue,
                                                   float* __restrict__ nn) {
    const int i = blockIdx.x, j = threadIdx.x;
    unsigned int qidx = 0xFFFFFFFFu - (unsigned int)(packed[i] & 0xFFFFFFFFull);
    nn[(size_t)i * DIMK + j] = queue[(size_t)qidx * DIMK + j];
}

// diag[i] = 10 * dot(Arow_i, Brow_i)
__global__ __launch_bounds__(256) void diag_dot(const float* __restrict__ Ar,
                                                const float* __restrict__ Br,
                                                float* __restrict__ out) {
    __shared__ float red[256];
    const int i = blockIdx.x, j = threadIdx.x;
    red[j] = Ar[(size_t)i * DIMK + j] * Br[(size_t)i * DIMK + j];
    __syncthreads();
    for (int s = 128; s > 0; s >>= 1) {
        if (j < s) red[j] += red[j + s];
        __syncthreads();
    }
    if (j == 0) out[i] = red[0] * SCALE_T;
}

__global__ __launch_bounds__(256) void final_loss(const float* __restrict__ d1,
                                                  const float* __restrict__ d2,
                                                  const float* __restrict__ sr1,
                                                  const float* __restrict__ sc1,
                                                  const float* __restrict__ sr2,
                                                  const float* __restrict__ sc2,
                                                  float* __restrict__ out) {
    __shared__ float red[256];
    const int t = threadIdx.x;
    float acc = 0.f;
    for (int i = t; i < BROWS; i += 256) {
        acc += 2.f * (d1[i] + d2[i]) - logf(sr1[i]) - logf(sc1[i]) - logf(sr2[i]) - logf(sc2[i]);
    }
    red[t] = acc;
    __syncthreads();
    for (int s = 128; s > 0; s >>= 1) {
        if (t < s) red[t] += red[t + s];
        __syncthreads();
    }
    if (t == 0) out[0] = -red[0] / (4.0f * (float)BROWS);
}

extern "C" void kernel_launch(void* const* d_in, const int* in_sizes, int n_in,
                              void* d_out, int out_size, void* d_ws, size_t ws_size,
                              hipStream_t stream) {
    const float* f1 = (const float*)d_in[0];
    const float* f2 = (const float*)d_in[1];
    const float* W1 = (const float*)d_in[2];
    const float* b1 = (const float*)d_in[3];
    const float* W2 = (const float*)d_in[4];
    const float* b2 = (const float*)d_in[5];
    const float* queue = (const float*)d_in[6];
    float* out = (float*)d_out;

    float* p1 = (float*)d_ws;
    float* p2 = p1 + (size_t)BROWS * DIMK;
    float* h = p2 + (size_t)BROWS * DIMK;
    float* nn1 = h + (size_t)BROWS * DIMK;
    float* nn2 = nn1 + (size_t)BROWS * DIMK;
    unsigned long long* amax1 = (unsigned long long*)(nn2 + (size_t)BROWS * DIMK);
    unsigned long long* amax2 = amax1 + BROWS;
    float* sums = (float*)(amax2 + BROWS);
    float* s_r1 = sums;
    float* s_c1 = sums + BROWS;
    float* s_r2 = sums + 2 * BROWS;
    float* s_c2 = sums + 3 * BROWS;
    float* diag1 = sums + 4 * BROWS;
    float* diag2 = diag1 + BROWS;

    // zero the atomic-reduction region (argmax u64s + exp-sums) every launch
    hipMemsetAsync(amax1, 0,
                   2 * BROWS * sizeof(unsigned long long) + 4 * BROWS * sizeof(float), stream);

    proj_relu<<<BROWS, 256, 0, stream>>>(f1, W1, b1, h);
    proj_norm<<<BROWS, 256, 0, stream>>>(h, W2, b2, p1);
    proj_relu<<<BROWS, 256, 0, stream>>>(f2, W1, b1, h);
    proj_norm<<<BROWS, 256, 0, stream>>>(h, W2, b2, p2);

    dim3 gl(QN / 64, BROWS / 64);
    tile_gemm_reduce<0><<<gl, 256, 0, stream>>>(p1, queue, amax1, nullptr);
    tile_gemm_reduce<0><<<gl, 256, 0, stream>>>(p2, queue, amax2, nullptr);

    gather_rows<<<BROWS, 256, 0, stream>>>(amax1, queue, nn1);
    gather_rows<<<BROWS, 256, 0, stream>>>(amax2, queue, nn2);

    dim3 gs(BROWS / 64, BROWS / 64);
    tile_gemm_reduce<1><<<gs, 256, 0, stream>>>(nn1, p2, nullptr, s_r1);
    tile_gemm_reduce<1><<<gs, 256, 0, stream>>>(p2, nn1, nullptr, s_c1);
    tile_gemm_reduce<1><<<gs, 256, 0, stream>>>(nn2, p1, nullptr, s_r2);
    tile_gemm_reduce<1><<<gs, 256, 0, stream>>>(p1, nn2, nullptr, s_c2);

    diag_dot<<<BROWS, 256, 0, stream>>>(nn1, p2, diag1);
    diag_dot<<<BROWS, 256, 0, stream>>>(nn2, p1, diag2);

    final_loss<<<1, 256, 0, stream>>>(diag1, diag2, s_r1, s_c1, s_r2, s_c2, out);
}

// Round 2
// 313.197 us; speedup vs baseline: 7.9217x; 7.9217x over previous
//
#include <hip/hip_runtime.h>

typedef unsigned short ushort_t;
typedef unsigned long long u64_t;
typedef __attribute__((ext_vector_type(8))) short v8bf;
typedef __attribute__((ext_vector_type(8))) unsigned short v8us;
typedef __attribute__((ext_vector_type(4))) float v4f;

#define BROWS 4096
#define DIMK 256
#define QN 32768
#define EXPSCALE 14.426950408889634f   // 10 * log2(e)

__device__ __forceinline__ ushort_t f2bf(float f) {
    unsigned u = __float_as_uint(f);
    return (ushort_t)((u + 0x7FFFu + ((u >> 16) & 1u)) >> 16);   // RNE, no NaN in data
}
__device__ __forceinline__ float bf2f(ushort_t u) {
    return __uint_as_float(((unsigned)u) << 16);
}
__device__ __forceinline__ unsigned enc_f32(float f) {
    unsigned b = __float_as_uint(f);
    return b ^ ((unsigned)(((int)b) >> 31) | 0x80000000u);   // monotone u32 encoding
}
__device__ __forceinline__ u64_t shfl_xor_u64(u64_t v, int off) {
    unsigned lo = (unsigned)(v & 0xFFFFFFFFull);
    unsigned hi = (unsigned)(v >> 32);
    lo = (unsigned)__shfl_xor((int)lo, off, 64);
    hi = (unsigned)__shfl_xor((int)hi, off, 64);
    return ((u64_t)hi << 32) | (u64_t)lo;
}
__device__ __forceinline__ void gload_lds16(const void* g, void* l) {
    __builtin_amdgcn_global_load_lds((const __attribute__((address_space(1))) void*)g,
                                     (__attribute__((address_space(3))) void*)l, 16, 0, 0);
}

// ---- bf16 conversion of the queue ----
__global__ __launch_bounds__(256) void conv_bf16(const float* __restrict__ in,
                                                 ushort_t* __restrict__ out) {
    const size_t i = ((size_t)blockIdx.x * 256 + threadIdx.x) * 8;
    float4 x = *(const float4*)&in[i];
    float4 y = *(const float4*)&in[i + 4];
    v8us o;
    o[0] = f2bf(x.x); o[1] = f2bf(x.y); o[2] = f2bf(x.z); o[3] = f2bf(x.w);
    o[4] = f2bf(y.x); o[5] = f2bf(y.y); o[6] = f2bf(y.z); o[7] = f2bf(y.w);
    *(v8us*)&out[i] = o;
}

// ---- projections (fp32 VALU, 16 rows/block to amortize W reads) ----
__global__ __launch_bounds__(256) void proj_relu16(const float* __restrict__ F,
                                                   const float* __restrict__ W,
                                                   const float* __restrict__ bias,
                                                   float* __restrict__ H) {
    __shared__ float fr[16][256];
    const int r0 = blockIdx.x << 4, j = threadIdx.x;
#pragma unroll
    for (int r = 0; r < 16; ++r) fr[r][j] = F[(size_t)(r0 + r) * DIMK + j];
    __syncthreads();
    float acc[16];
    const float bj = bias[j];
#pragma unroll
    for (int r = 0; r < 16; ++r) acc[r] = bj;
    for (int k = 0; k < DIMK; k += 4) {
        const float w0 = W[(k + 0) * DIMK + j];
        const float w1 = W[(k + 1) * DIMK + j];
        const float w2 = W[(k + 2) * DIMK + j];
        const float w3 = W[(k + 3) * DIMK + j];
#pragma unroll
        for (int r = 0; r < 16; ++r) {
            float4 f = *(const float4*)&fr[r][k];
            acc[r] = fmaf(f.x, w0, acc[r]);
            acc[r] = fmaf(f.y, w1, acc[r]);
            acc[r] = fmaf(f.z, w2, acc[r]);
            acc[r] = fmaf(f.w, w3, acc[r]);
        }
    }
#pragma unroll
    for (int r = 0; r < 16; ++r)
        H[(size_t)(r0 + r) * DIMK + j] = acc[r] > 0.f ? acc[r] : 0.f;
}

__global__ __launch_bounds__(256) void proj_norm16(const float* __restrict__ H,
                                                   const float* __restrict__ W,
                                                   const float* __restrict__ bias,
                                                   ushort_t* __restrict__ P) {
    __shared__ float hr[16][256];
    __shared__ float partial[4][16];
    const int r0 = blockIdx.x << 4, j = threadIdx.x;
    const int w = j >> 6, l = j & 63;
#pragma unroll
    for (int r = 0; r < 16; ++r) hr[r][j] = H[(size_t)(r0 + r) * DIMK + j];
    __syncthreads();
    float acc[16];
    const float bj = bias[j];
#pragma unroll
    for (int r = 0; r < 16; ++r) acc[r] = bj;
    for (int k = 0; k < DIMK; k += 4) {
        const float w0 = W[(k + 0) * DIMK + j];
        const float w1 = W[(k + 1) * DIMK + j];
        const float w2 = W[(k + 2) * DIMK + j];
        const float w3 = W[(k + 3) * DIMK + j];
#pragma unroll
        for (int r = 0; r < 16; ++r) {
            float4 f = *(const float4*)&hr[r][k];
            acc[r] = fmaf(f.x, w0, acc[r]);
            acc[r] = fmaf(f.y, w1, acc[r]);
            acc[r] = fmaf(f.z, w2, acc[r]);
            acc[r] = fmaf(f.w, w3, acc[r]);
        }
    }
#pragma unroll
    for (int r = 0; r < 16; ++r) {
        float s = acc[r] * acc[r];
        s += __shfl_xor(s, 1);  s += __shfl_xor(s, 2);
        s += __shfl_xor(s, 4);  s += __shfl_xor(s, 8);
        s += __shfl_xor(s, 16); s += __shfl_xor(s, 32);
        if (l == 0) partial[w][r] = s;
    }
    __syncthreads();
#pragma unroll
    for (int r = 0; r < 16; ++r) {
        const float tot = partial[0][r] + partial[1][r] + partial[2][r] + partial[3][r];
        const float inv = 1.f / fmaxf(sqrtf(tot), 1e-12f);
        P[(size_t)(r0 + r) * DIMK + j] = f2bf(acc[r] * inv);
    }
}

// ---- shared MFMA tile helpers ----
// stage 128 rows x 64 k (bf16) from row-major [*, 256]; XOR-swizzled slots via
// pre-swizzled GLOBAL source (global_load_lds dest must stay linear)
__device__ __forceinline__ void stage_tile(const ushort_t* __restrict__ M, int row_base,
                                           int k0, ushort_t* lds, int w, int l) {
#pragma unroll
    for (int i = 0; i < 4; ++i) {
        const int blk = (w << 2) + i;
        const int row = (blk << 3) + (l >> 3);
        const int srcslot = (l ^ row) & 7;
        gload_lds16(&M[(size_t)(row_base + row) * DIMK + k0 + (srcslot << 3)],
                    &lds[blk << 9]);
    }
}
// read MFMA A/B fragment: lane holds row (frow + l&15), 8 k at (hh*4 + l>>4)*8
__device__ __forceinline__ v8bf read_frag(const ushort_t* lds, int frow, int hh, int l) {
    const int row = frow + (l & 15);
    const int kslot = (hh << 2) + (l >> 4);
    const int slot = kslot ^ (row & 7);
    return *(const v8bf*)&lds[(row << 6) + (slot << 3)];
}

// ---- NN lookup: sims = P(128 rows) x Q^T, fused per-row argmax over 2048-col chunk ----
__global__ __launch_bounds__(256) void nn_argmax(const ushort_t* __restrict__ P,
                                                 const ushort_t* __restrict__ Q,
                                                 u64_t* __restrict__ packed) {
    __shared__ __align__(16) ushort_t As[128 * 64];
    __shared__ __align__(16) ushort_t Bs[128 * 64];
    const int tid = threadIdx.x;
    const int w = tid >> 6, l = tid & 63;
    const int wr = w >> 1, wc = w & 1;
    const int row0 = blockIdx.y << 7;
    const int qbase = blockIdx.x << 11;   // 16 tiles of 128 cols

    float vbest[4][4];
    int cbest[4][4];
#pragma unroll
    for (int a = 0; a < 4; ++a)
#pragma unroll
        for (int b = 0; b < 4; ++b) { vbest[a][b] = -3e38f; cbest[a][b] = 0; }

    for (int t = 0; t < 16; ++t) {
        const int qrow0 = qbase + (t << 7);
        const v4f vzero = {0.f, 0.f, 0.f, 0.f};
        v4f acc[4][4];
#pragma unroll
        for (int a = 0; a < 4; ++a)
#pragma unroll
            for (int b = 0; b < 4; ++b) acc[a][b] = vzero;

        for (int k0 = 0; k0 < DIMK; k0 += 64) {
            stage_tile(P, row0, k0, As, w, l);
            stage_tile(Q, qrow0, k0, Bs, w, l);
            __syncthreads();
#pragma unroll
            for (int hh = 0; hh < 2; ++hh) {
                v8bf av[4], bv[4];
#pragma unroll
                for (int mi = 0; mi < 4; ++mi) av[mi] = read_frag(As, (wr << 6) + (mi << 4), hh, l);
#pragma unroll
                for (int nj = 0; nj < 4; ++nj) bv[nj] = read_frag(Bs, (wc << 6) + (nj << 4), hh, l);
#pragma unroll
                for (int mi = 0; mi < 4; ++mi)
#pragma unroll
                    for (int nj = 0; nj < 4; ++nj)
                        acc[mi][nj] = __builtin_amdgcn_mfma_f32_16x16x32_bf16(
                            av[mi], bv[nj], acc[mi][nj], 0, 0, 0);
            }
            __syncthreads();
        }
        // cheap per-tile running-argmax update (strict > keeps earliest col, matching np)
        const int coltile = qrow0 + (wc << 6);
#pragma unroll
        for (int mi = 0; mi < 4; ++mi)
#pragma unroll
            for (int r = 0; r < 4; ++r) {
                float v = acc[mi][0][r]; int c = coltile;
                if (acc[mi][1][r] > v) { v = acc[mi][1][r]; c = coltile + 16; }
                if (acc[mi][2][r] > v) { v = acc[mi][2][r]; c = coltile + 32; }
                if (acc[mi][3][r] > v) { v = acc[mi][3][r]; c = coltile + 48; }
                if (v > vbest[mi][r]) { vbest[mi][r] = v; cbest[mi][r] = c; }
            }
    }
    // once per block: cross-lane reduce + atomic (tie-break: smaller col wins)
#pragma unroll
    for (int mi = 0; mi < 4; ++mi)
#pragma unroll
        for (int r = 0; r < 4; ++r) {
            const unsigned col = (unsigned)(cbest[mi][r] + (l & 15));
            u64_t pk = ((u64_t)enc_f32(vbest[mi][r]) << 32) | (u64_t)(0xFFFFFFFFu - col);
#pragma unroll
            for (int off = 1; off < 16; off <<= 1) {
                u64_t o = shfl_xor_u64(pk, off);
                if (o > pk) pk = o;
            }
            if ((l & 15) == 0)
                atomicMax(&packed[row0 + (wr << 6) + (mi << 4) + ((l >> 4) << 2) + r], pk);
        }
}

// ---- S = A x B^T, fused row-sums AND col-sums of exp(10*S) (s122 = s121^T) ----
__global__ __launch_bounds__(256) void lse_gemm(const ushort_t* __restrict__ A,
                                                const ushort_t* __restrict__ B,
                                                float* __restrict__ sr,
                                                float* __restrict__ sc) {
    __shared__ __align__(16) ushort_t As[128 * 64];
    __shared__ __align__(16) ushort_t Bs[128 * 64];
    const int tid = threadIdx.x;
    const int w = tid >> 6, l = tid & 63;
    const int wr = w >> 1, wc = w & 1;
    const int row0 = blockIdx.y << 7;
    const int col0 = blockIdx.x << 7;
    const v4f vzero = {0.f, 0.f, 0.f, 0.f};
    v4f acc[4][4];
#pragma unroll
    for (int a = 0; a < 4; ++a)
#pragma unroll
        for (int b = 0; b < 4; ++b) acc[a][b] = vzero;

    for (int k0 = 0; k0 < DIMK; k0 += 64) {
        stage_tile(A, row0, k0, As, w, l);
        stage_tile(B, col0, k0, Bs, w, l);
        __syncthreads();
#pragma unroll
        for (int hh = 0; hh < 2; ++hh) {
            v8bf av[4], bv[4];
#pragma unroll
            for (int mi = 0; mi < 4; ++mi) av[mi] = read_frag(As, (wr << 6) + (mi << 4), hh, l);
#pragma unroll
            for (int nj = 0; nj < 4; ++nj) bv[nj] = read_frag(Bs, (wc << 6) + (nj << 4), hh, l);
#pragma unroll
            for (int mi = 0; mi < 4; ++mi)
#pragma unroll
                for (int nj = 0; nj < 4; ++nj)
                    acc[mi][nj] = __builtin_amdgcn_mfma_f32_16x16x32_bf16(
                        av[mi], bv[nj], acc[mi][nj], 0, 0, 0);
        }
        __syncthreads();
    }
    // exp(10*s); |10*s| <= ~10.2 so no max-subtraction needed in fp32
#pragma unroll
    for (int mi = 0; mi < 4; ++mi)
#pragma unroll
        for (int nj = 0; nj < 4; ++nj) {
            v4f t = acc[mi][nj];
            t[0] = exp2f(t[0] * EXPSCALE);
            t[1] = exp2f(t[1] * EXPSCALE);
            t[2] = exp2f(t[2] * EXPSCALE);
            t[3] = exp2f(t[3] * EXPSCALE);
            acc[mi][nj] = t;
        }
    // row sums (C row = (l>>4)*4 + r, within 16-lane groups)
#pragma unroll
    for (int mi = 0; mi < 4; ++mi)
#pragma unroll
        for (int r = 0; r < 4; ++r) {
            float s = acc[mi][0][r] + acc[mi][1][r] + acc[mi][2][r] + acc[mi][3][r];
            s += __shfl_xor(s, 1); s += __shfl_xor(s, 2);
            s += __shfl_xor(s, 4); s += __shfl_xor(s, 8);
            if ((l & 15) == 0)
                atomicAdd(&sr[row0 + (wr << 6) + (mi << 4) + ((l >> 4) << 2) + r], s);
        }
    // col sums (C col = l&15 within frag nj)
#pragma unroll
    for (int nj = 0; nj < 4; ++nj) {
        float s = 0.f;
#pragma unroll
        for (int mi = 0; mi < 4; ++mi)
#pragma unroll
            for (int r = 0; r < 4; ++r) s += acc[mi][nj][r];
        s += __shfl_xor(s, 16); s += __shfl_xor(s, 32);
        if (l < 16) atomicAdd(&sc[col0 + (wc << 6) + (nj << 4) + l], s);
    }
}

// ---- small epilogue kernels ----
__global__ __launch_bounds__(256) void gather_bf(const u64_t* __restrict__ packed,
                                                 const ushort_t* __restrict__ qb,
                                                 ushort_t* __restrict__ nn) {
    const int i = blockIdx.x, j = threadIdx.x;
    const unsigned idx = 0xFFFFFFFFu - (unsigned)(packed[i] & 0xFFFFFFFFull);
    nn[(size_t)i * DIMK + j] = qb[(size_t)idx * DIMK + j];
}

__global__ __launch_bounds__(256) void diag_dot_bf(const ushort_t* __restrict__ A,
                                                   const ushort_t* __restrict__ B,
                                                   float* __restrict__ out) {
    __shared__ float red[256];
    const int i = blockIdx.x, j = threadIdx.x;
    red[j] = bf2f(A[(size_t)i * DIMK + j]) * bf2f(B[(size_t)i * DIMK + j]);
    __syncthreads();
    for (int s = 128; s > 0; s >>= 1) {
        if (j < s) red[j] += red[j + s];
        __syncthreads();
    }
    if (j == 0) out[i] = red[0] * 10.0f;
}

__global__ __launch_bounds__(256) void final_loss(const float* __restrict__ d1,
                                                  const float* __restrict__ d2,
                                                  const float* __restrict__ sr1,
                                                  const float* __restrict__ sc1,
                                                  const float* __restrict__ sr2,
                                                  const float* __restrict__ sc2,
                                                  float* __restrict__ out) {
    __shared__ float red[256];
    const int t = threadIdx.x;
    float acc = 0.f;
    for (int i = t; i < BROWS; i += 256) {
        acc += 2.f * (d1[i] + d2[i]) - logf(sr1[i]) - logf(sc1[i]) - logf(sr2[i]) - logf(sc2[i]);
    }
    red[t] = acc;
    __syncthreads();
    for (int s = 128; s > 0; s >>= 1) {
        if (t < s) red[t] += red[t + s];
        __syncthreads();
    }
    if (t == 0) out[0] = -red[0] / (4.0f * (float)BROWS);
}

extern "C" void kernel_launch(void* const* d_in, const int* in_sizes, int n_in,
                              void* d_out, int out_size, void* d_ws, size_t ws_size,
                              hipStream_t stream) {
    const float* f1 = (const float*)d_in[0];
    const float* f2 = (const float*)d_in[1];
    const float* W1 = (const float*)d_in[2];
    const float* b1 = (const float*)d_in[3];
    const float* W2 = (const float*)d_in[4];
    const float* b2 = (const float*)d_in[5];
    const float* queue = (const float*)d_in[6];
    float* out = (float*)d_out;

    char* ws = (char*)d_ws;
    float* h        = (float*)ws;                          // 4 MB
    ushort_t* p1b   = (ushort_t*)(ws + (4ull << 20));      // 2 MB each
    ushort_t* p2b   = (ushort_t*)(ws + (6ull << 20));
    ushort_t* nn1b  = (ushort_t*)(ws + (8ull << 20));
    ushort_t* nn2b  = (ushort_t*)(ws + (10ull << 20));
    ushort_t* qb    = (ushort_t*)(ws + (12ull << 20));     // 16 MB
    u64_t* packed1  = (u64_t*)(ws + (28ull << 20));        // 32 KB
    u64_t* packed2  = packed1 + BROWS;                     // 32 KB
    float* s_r1     = (float*)(packed2 + BROWS);
    float* s_c1     = s_r1 + BROWS;
    float* s_r2     = s_c1 + BROWS;
    float* s_c2     = s_r2 + BROWS;
    float* diag1    = s_c2 + BROWS;
    float* diag2    = diag1 + BROWS;

    // zero atomic-reduction targets (packed argmax + exp sums) every launch
    hipMemsetAsync(packed1, 0, 2 * BROWS * sizeof(u64_t) + 4 * BROWS * sizeof(float), stream);

    conv_bf16<<<(QN * DIMK) / 2048, 256, 0, stream>>>(queue, qb);

    proj_relu16<<<BROWS / 16, 256, 0, stream>>>(f1, W1, b1, h);
    proj_norm16<<<BROWS / 16, 256, 0, stream>>>(h, W2, b2, p1b);
    proj_relu16<<<BROWS / 16, 256, 0, stream>>>(f2, W1, b1, h);
    proj_norm16<<<BROWS / 16, 256, 0, stream>>>(h, W2, b2, p2b);

    dim3 ga(QN / 2048, BROWS / 128);   // (16, 32) = 512 blocks = 2/CU
    nn_argmax<<<ga, 256, 0, stream>>>(p1b, qb, packed1);
    nn_argmax<<<ga, 256, 0, stream>>>(p2b, qb, packed2);

    gather_bf<<<BROWS, 256, 0, stream>>>(packed1, qb, nn1b);
    gather_bf<<<BROWS, 256, 0, stream>>>(packed2, qb, nn2b);

    dim3 gs(BROWS / 128, BROWS / 128);  // (32, 32)
    lse_gemm<<<gs, 256, 0, stream>>>(nn1b, p2b, s_r1, s_c1);
    lse_gemm<<<gs, 256, 0, stream>>>(nn2b, p1b, s_r2, s_c2);

    diag_dot_bf<<<BROWS, 256, 0, stream>>>(nn1b, p2b, diag1);
    diag_dot_bf<<<BROWS, 256, 0, stream>>>(nn2b, p1b, diag2);

    final_loss<<<1, 256, 0, stream>>>(diag1, diag2, s_r1, s_c1, s_r2, s_c2, out);
}